// Round 3
// baseline (996.122 us; speedup 1.0000x reference)
//
#include <hip/hip_runtime.h>
#include <stdint.h>

namespace {
constexpr int kB  = 16384;  // batch
constexpr int kN  = 128;    // nodes
constexpr int kI  = 3;      // data electrodes
constexpr int kC  = 4;      // control electrodes
constexpr int kE  = 7;      // total electrodes
constexpr int kH  = 90;     // hidden width
constexpr int kL  = 3;      // hidden layers
constexpr int BT  = 128;    // batch rows per block
constexpr int KP  = 96;     // padded H (multiple of 32 for MFMA K, of 16 for N-tiles)
constexpr int LDP = 104;    // LDS row stride in elements: 208 B (16B-aligned), 2-way-bank-free
}

typedef __attribute__((ext_vector_type(8))) short bf16x8;
typedef __attribute__((ext_vector_type(4))) float f32x4;

__device__ __forceinline__ float bf2f(ushort u) {
  union { uint32_t i; float f; } v; v.i = ((uint32_t)u) << 16; return v.f;
}
__device__ __forceinline__ ushort f2bf(float f) {
  union { float f; uint32_t i; } v; v.f = f;
  uint32_t u = v.i;
  u += 0x7FFFu + ((u >> 16) & 1u);   // round-to-nearest-even
  return (ushort)(u >> 16);
}

__global__ __launch_bounds__(256) void dnpu_kernel(
    const float* __restrict__ x, const float* __restrict__ controls,
    const float* __restrict__ W_in, const float* __restrict__ b_in,
    const float* __restrict__ W_hid, const float* __restrict__ b_hid,
    const float* __restrict__ W_out, const float* __restrict__ b_out,
    float* __restrict__ out)
{
  // __align__(16): bf16x8 fragment loads are ds_read_b128 — base must be 16B aligned.
  __shared__ __align__(16) ushort hbuf[BT][LDP];  // activations [row][k] (bf16)
  __shared__ __align__(16) ushort wbuf[KP][LDP];  // Wt[j_out][k_in] (bf16)
  __shared__ float biasbuf[2][KP];                // double-buffered (WAR race fix)
  __shared__ float woutbuf[KP];
  __shared__ float s_bout;

  const int tid  = threadIdx.x;
  const int node = blockIdx.x & (kN - 1);
  const int m0   = (int)(blockIdx.x >> 7) * BT;
  const int wave = tid >> 6;
  const int lane = tid & 63;
  const int quad = lane >> 4;
  const int l16  = lane & 15;

  // ---- stage input layer: e = [x | controls] zero-padded to K=32 ----
  for (int idx = tid; idx < BT * 32; idx += 256) {
    int r = idx >> 5, c = idx & 31;
    ushort v = 0;
    if (c < kI)      v = f2bf(x[(size_t)(m0 + r) * (kN * kI) + node * kI + c]);
    else if (c < kE) v = f2bf(controls[node * kC + (c - kI)]);
    hbuf[r][c] = v;
  }
  // W_in^T: wbuf[j][k] = W_in[node][k][j], zero-padded (j<96, k<32)
  for (int idx = tid; idx < KP * 32; idx += 256) {
    int j = idx % KP, k = idx / KP;
    ushort v = 0;
    if (j < kH && k < kE) v = f2bf(W_in[(node * kE + k) * kH + j]);
    wbuf[j][k] = v;
  }
  for (int j = tid; j < KP; j += 256)
    biasbuf[0][j] = (j < kH) ? b_in[node * kH + j] : 0.f;
  __syncthreads();

  f32x4 acc[2][6];

  auto zero_acc = [&]() {
#pragma unroll
    for (int mt = 0; mt < 2; ++mt)
#pragma unroll
      for (int nt = 0; nt < 6; ++nt)
        acc[mt][nt] = (f32x4){0.f, 0.f, 0.f, 0.f};
  };

  // A[m=lane&15][k=quad*8+j]; B[k=quad*8+j][n=lane&15]; D col=lane&15, row=quad*4+reg
  auto run_gemm = [&](int ksteps) {
    for (int ks = 0; ks < ksteps; ++ks) {
      const int koff = ks * 32 + quad * 8;
      bf16x8 a0 = *(const bf16x8*)&hbuf[wave * 32 + l16][koff];
      bf16x8 a1 = *(const bf16x8*)&hbuf[wave * 32 + 16 + l16][koff];
#pragma unroll
      for (int nt = 0; nt < 6; ++nt) {
        bf16x8 b = *(const bf16x8*)&wbuf[nt * 16 + l16][koff];
        acc[0][nt] = __builtin_amdgcn_mfma_f32_16x16x32_bf16(a0, b, acc[0][nt], 0, 0, 0);
        acc[1][nt] = __builtin_amdgcn_mfma_f32_16x16x32_bf16(a1, b, acc[1][nt], 0, 0, 0);
      }
    }
  };

  auto write_h = [&](int parity) {
#pragma unroll
    for (int mt = 0; mt < 2; ++mt)
#pragma unroll
      for (int nt = 0; nt < 6; ++nt) {
        const int col = nt * 16 + l16;
        const float bv = biasbuf[parity][col];
#pragma unroll
        for (int r = 0; r < 4; ++r) {
          const int row = wave * 32 + mt * 16 + quad * 4 + r;
          float v = acc[mt][nt][r] + bv;
          hbuf[row][col] = f2bf(fmaxf(v, 0.f));
        }
      }
  };

  zero_acc();
  run_gemm(1);  // input layer, K=32 (cols 7..31 zero)

  for (int l = 0; l < kL; ++l) {
    __syncthreads();          // all waves done reading hbuf/wbuf of previous gemm
    write_h(l & 1);           // relu(acc + bias) -> hbuf (own wave's rows only)
    // stage W_hid[l]^T into wbuf; bias into the OTHER parity slot (no race)
    {
      const float* W = W_hid + ((size_t)(l * kN + node) * kH) * kH;
      for (int idx = tid; idx < KP * KP; idx += 256) {
        int j = idx % KP, k = idx / KP;
        ushort v = 0;
        if (j < kH && k < kH) v = f2bf(W[k * kH + j]);
        wbuf[j][k] = v;
      }
      for (int j = tid; j < KP; j += 256)
        biasbuf[(l + 1) & 1][j] = (j < kH) ? b_hid[(size_t)(l * kN + node) * kH + j] : 0.f;
    }
    zero_acc();
    __syncthreads();
    run_gemm(3);  // K=96 (cols 90..95 of h and rows 90..95 of Wt are zero)
  }

  __syncthreads();
  write_h(kL & 1);  // third hidden layer activations -> hbuf
  for (int j = tid; j < KP; j += 256)
    woutbuf[j] = (j < kH) ? W_out[node * kH + j] : 0.f;
  if (tid == 0) s_bout = b_out[node];
  __syncthreads();

  // output: out[b][node] = h . W_out + b_out   (fp32 store)
  if (tid < BT) {
    float sum = s_bout;
#pragma unroll
    for (int c = 0; c < KP; c += 8) {
      bf16x8 hv = *(const bf16x8*)&hbuf[tid][c];
#pragma unroll
      for (int j = 0; j < 8; ++j)
        sum += bf2f((ushort)hv[j]) * woutbuf[c + j];
    }
    out[(size_t)(m0 + tid) * kN + node] = sum;
  }
}

extern "C" void kernel_launch(void* const* d_in, const int* in_sizes, int n_in,
                              void* d_out, int out_size, void* d_ws, size_t ws_size,
                              hipStream_t stream) {
  const float* x        = (const float*)d_in[0];
  const float* controls = (const float*)d_in[1];
  const float* W_in     = (const float*)d_in[2];
  const float* b_in     = (const float*)d_in[3];
  const float* W_hid    = (const float*)d_in[4];
  const float* b_hid    = (const float*)d_in[5];
  const float* W_out    = (const float*)d_in[6];
  const float* b_out    = (const float*)d_in[7];
  float* out = (float*)d_out;

  dim3 grid((kB / BT) * kN);   // 128 batch tiles x 128 nodes = 16384 blocks
  hipLaunchKernelGGL(dnpu_kernel, grid, dim3(256), 0, stream,
                     x, controls, W_in, b_in, W_hid, b_hid, W_out, b_out, out);
}

// Round 4
// 464.468 us; speedup vs baseline: 2.1447x; 2.1447x over previous
//
#include <hip/hip_runtime.h>
#include <stdint.h>

namespace {
constexpr int kB  = 16384;  // batch
constexpr int kN  = 128;    // nodes
constexpr int kI  = 3;      // data electrodes
constexpr int kC  = 4;      // control electrodes
constexpr int kE  = 7;      // total electrodes
constexpr int kH  = 90;     // hidden width
constexpr int kL  = 3;      // hidden layers
constexpr int BT  = 128;    // batch rows per block
constexpr int KP  = 96;     // padded H
constexpr int LDP = 104;    // LDS row stride (208 B: 16B-aligned, 2-way-bank-free)
constexpr int TILE_ELEMS  = KP * LDP;              // 9984 ushorts per (layer,node) tile
constexpr int TILE_CHUNKS = TILE_ELEMS / 8;        // 1248 bf16x8 chunks
constexpr size_t WT_BYTES = (size_t)4 * kN * TILE_ELEMS * 2;  // 10,223,616
constexpr size_t WOUT_OFF = WT_BYTES;              // 128 nodes x 96 bf16
}

typedef __attribute__((ext_vector_type(8))) short bf16x8;
typedef __attribute__((ext_vector_type(4))) float f32x4;

__device__ __forceinline__ float bf2f(ushort u) {
  union { uint32_t i; float f; } v; v.i = ((uint32_t)u) << 16; return v.f;
}
__device__ __forceinline__ ushort f2bf(float f) {
  union { float f; uint32_t i; } v; v.f = f;
  uint32_t u = v.i;
  u += 0x7FFFu + ((u >> 16) & 1u);   // round-to-nearest-even
  return (ushort)(u >> 16);
}

// ---- preprocess: write the exact LDS image per (layer,node):
// Wt[j][k] bf16, stride LDP; row k==KSRC carries the bias (augmented-K trick);
// everything else out of range is 0.
__global__ __launch_bounds__(256) void prep_weights(
    const float* __restrict__ W_in, const float* __restrict__ b_in,
    const float* __restrict__ W_hid, const float* __restrict__ b_hid,
    ushort* __restrict__ wt)
{
  __shared__ float ldsw[kH][kH + 1];
  __shared__ float ldsb[kH];
  const int tid   = threadIdx.x;
  const int node  = blockIdx.x & (kN - 1);
  const int layer = blockIdx.x >> 7;               // 0..3
  const int ksrc  = (layer == 0) ? kE : kH;
  const float* src;
  const float* bsrc;
  if (layer == 0) { src = W_in + (size_t)node * kE * kH; bsrc = b_in + (size_t)node * kH; }
  else {
    int l = layer - 1;
    src  = W_hid + (size_t)(l * kN + node) * kH * kH;
    bsrc = b_hid + (size_t)(l * kN + node) * kH;
  }
  for (int idx = tid; idx < ksrc * kH; idx += 256)   // coalesced read, [k][j] in LDS
    ldsw[idx / kH][idx % kH] = src[idx];
  if (tid < kH) ldsb[tid] = bsrc[tid];
  __syncthreads();
  ushort* dst = wt + (size_t)blockIdx.x * TILE_ELEMS;  // blockIdx == layer*128+node
  for (int idx = tid; idx < TILE_ELEMS; idx += 256) {  // coalesced write
    int j = idx / LDP, k = idx % LDP;
    float v = 0.f;
    if (j < kH) {
      if (k < ksrc)       v = ldsw[k][j];
      else if (k == ksrc) v = ldsb[j];
    }
    dst[idx] = f2bf(v);
  }
}

// wout image per node: 96 bf16, [0..89]=W_out, [90]=b_out, rest 0.
__global__ __launch_bounds__(256) void prep_wout(
    const float* __restrict__ W_out, const float* __restrict__ b_out,
    ushort* __restrict__ wo)
{
  int idx = blockIdx.x * 256 + threadIdx.x;          // grid 48 -> 12288 = 128*96
  int node = idx / KP, j = idx % KP;
  float v = 0.f;
  if (j < kH)       v = W_out[node * kH + j];
  else if (j == kH) v = b_out[node];
  wo[idx] = f2bf(v);
}

__global__ __launch_bounds__(256) void dnpu_kernel(
    const float* __restrict__ x, const float* __restrict__ controls,
    const ushort* __restrict__ wt, const ushort* __restrict__ wo,
    float* __restrict__ out)
{
  __shared__ __align__(16) ushort hbuf[BT][LDP];  // activations [row][k] (bf16)
  __shared__ __align__(16) ushort wbuf[KP][LDP];  // Wt[j_out][k_in] (bf16)
  __shared__ __align__(16) ushort wobuf[KP];

  const int tid  = threadIdx.x;
  const int node = (int)(blockIdx.x >> 7);         // resident blocks share few nodes -> L2-hot tiles
  const int m0   = (int)(blockIdx.x & 127) * BT;
  const int wave = tid >> 6;
  const int lane = tid & 63;
  const int quad = lane >> 4;
  const int l16  = lane & 15;

  auto stage_w = [&](int lyr) {
    const bf16x8* src = (const bf16x8*)(wt + (size_t)(lyr * kN + node) * TILE_ELEMS);
    bf16x8* dst = (bf16x8*)&wbuf[0][0];
#pragma unroll
    for (int it = 0; it < 5; ++it) {
      int c = tid + it * 256;
      if (c < TILE_CHUNKS) dst[c] = src[c];
    }
  };

  // ---- stage input: e = [x0..x2, c0..c3, 1.0, 0...] (K=32) ----
  for (int idx = tid; idx < BT * 32; idx += 256) {
    int r = idx >> 5, c = idx & 31;
    ushort v = 0;
    if (c < kI)      v = f2bf(x[(size_t)(m0 + r) * (kN * kI) + node * kI + c]);
    else if (c < kE) v = f2bf(controls[node * kC + (c - kI)]);
    else if (c == kE) v = 0x3F80;                  // 1.0 -> bias row of the tile
    hbuf[r][c] = v;
  }
  stage_w(0);
  if (tid < KP / 8) ((bf16x8*)wobuf)[tid] = ((const bf16x8*)(wo + node * KP))[tid];
  __syncthreads();

  f32x4 acc[2][6];
  auto zero_acc = [&]() {
#pragma unroll
    for (int mt = 0; mt < 2; ++mt)
#pragma unroll
      for (int nt = 0; nt < 6; ++nt)
        acc[mt][nt] = (f32x4){0.f, 0.f, 0.f, 0.f};
  };

  // A[m=lane&15][k=quad*8+j]; B[k=quad*8+j][n=lane&15]; D col=lane&15, row=quad*4+reg
  auto run_gemm = [&](int ksteps) {
    for (int ks = 0; ks < ksteps; ++ks) {
      const int koff = ks * 32 + quad * 8;
      bf16x8 a0 = *(const bf16x8*)&hbuf[wave * 32 + l16][koff];
      bf16x8 a1 = *(const bf16x8*)&hbuf[wave * 32 + 16 + l16][koff];
#pragma unroll
      for (int nt = 0; nt < 6; ++nt) {
        bf16x8 b = *(const bf16x8*)&wbuf[nt * 16 + l16][koff];
        acc[0][nt] = __builtin_amdgcn_mfma_f32_16x16x32_bf16(a0, b, acc[0][nt], 0, 0, 0);
        acc[1][nt] = __builtin_amdgcn_mfma_f32_16x16x32_bf16(a1, b, acc[1][nt], 0, 0, 0);
      }
    }
  };

  // relu(acc) -> hbuf (bias already folded in via augmented K); col 90 := 1.0
  auto write_h = [&]() {
#pragma unroll
    for (int mt = 0; mt < 2; ++mt)
#pragma unroll
      for (int nt = 0; nt < 6; ++nt) {
        const int col = nt * 16 + l16;
#pragma unroll
        for (int r = 0; r < 4; ++r) {
          const int row = wave * 32 + mt * 16 + quad * 4 + r;
          float v = fmaxf(acc[mt][nt][r], 0.f);
          if (nt == 5 && l16 == 10) v = 1.0f;      // ones column (k=90) for next bias
          hbuf[row][col] = f2bf(v);
        }
      }
  };

  zero_acc();
  run_gemm(1);  // input layer, K=32

  for (int l = 0; l < kL; ++l) {
    __syncthreads();          // all waves done reading hbuf/wbuf
    write_h();
    stage_w(l + 1);
    zero_acc();
    __syncthreads();
    run_gemm(3);              // K=96 (k=90 carries the bias, 91..95 zero)
  }

  __syncthreads();
  write_h();                  // h3 -> hbuf (col 90 = 1.0 pairs with wout[90]=b_out)
  __syncthreads();

  if (tid < BT) {
    float sum = 0.f;
#pragma unroll
    for (int c = 0; c < KP; c += 8) {
      bf16x8 hv = *(const bf16x8*)&hbuf[tid][c];
      bf16x8 wv = *(const bf16x8*)&wobuf[c];
#pragma unroll
      for (int j = 0; j < 8; ++j)
        sum += bf2f((ushort)hv[j]) * bf2f((ushort)wv[j]);
    }
    out[(size_t)(m0 + tid) * kN + node] = sum;
  }
}

extern "C" void kernel_launch(void* const* d_in, const int* in_sizes, int n_in,
                              void* d_out, int out_size, void* d_ws, size_t ws_size,
                              hipStream_t stream) {
  const float* x        = (const float*)d_in[0];
  const float* controls = (const float*)d_in[1];
  const float* W_in     = (const float*)d_in[2];
  const float* b_in     = (const float*)d_in[3];
  const float* W_hid    = (const float*)d_in[4];
  const float* b_hid    = (const float*)d_in[5];
  const float* W_out    = (const float*)d_in[6];
  const float* b_out    = (const float*)d_in[7];
  float* out = (float*)d_out;

  ushort* wt = (ushort*)d_ws;
  ushort* wo = (ushort*)((char*)d_ws + WOUT_OFF);

  hipLaunchKernelGGL(prep_weights, dim3(4 * kN), dim3(256), 0, stream,
                     W_in, b_in, W_hid, b_hid, wt);
  hipLaunchKernelGGL(prep_wout, dim3(kN * KP / 256), dim3(256), 0, stream,
                     W_out, b_out, wo);

  dim3 grid((kB / BT) * kN);   // 16384 blocks: bid = node*128 + m_tile
  hipLaunchKernelGGL(dnpu_kernel, grid, dim3(256), 0, stream,
                     x, controls, wt, wo, out);
}

// Round 5
// 391.955 us; speedup vs baseline: 2.5414x; 1.1850x over previous
//
#include <hip/hip_runtime.h>
#include <stdint.h>

namespace {
constexpr int kB  = 16384;  // batch
constexpr int kN  = 128;    // nodes
constexpr int kI  = 3;      // data electrodes
constexpr int kC  = 4;      // control electrodes
constexpr int kE  = 7;      // total electrodes
constexpr int kH  = 90;     // hidden width
constexpr int kL  = 3;      // hidden layers
constexpr int BT  = 128;    // batch rows per block
constexpr int KP  = 96;     // padded H
constexpr int LDP = 104;    // LDS row stride (208 B: 16B-aligned, 2-way-bank-free)
constexpr int TILE_ELEMS  = KP * LDP;              // 9984 ushorts per (layer,node) tile
constexpr int TILE_CHUNKS = TILE_ELEMS / 8;        // 1248 bf16x8 chunks
constexpr size_t WT_BYTES = (size_t)4 * kN * TILE_ELEMS * 2;
constexpr size_t WOUT_OFF = WT_BYTES;              // 128 nodes x 96 bf16
}

typedef __attribute__((ext_vector_type(8))) short bf16x8;
typedef __attribute__((ext_vector_type(4))) float f32x4;

__device__ __forceinline__ float bf2f(ushort u) {
  union { uint32_t i; float f; } v; v.i = ((uint32_t)u) << 16; return v.f;
}
__device__ __forceinline__ ushort f2bf(float f) {
  union { float f; uint32_t i; } v; v.f = f;
  uint32_t u = v.i;
  u += 0x7FFFu + ((u >> 16) & 1u);
  return (ushort)(u >> 16);
}
// pack two floats -> packed bf16 dword (lo in bits 0..15)
__device__ __forceinline__ uint32_t pack_bf16(float lo, float hi) {
#if __has_builtin(__builtin_amdgcn_cvt_pk_bf16_f32)
  auto r = __builtin_amdgcn_cvt_pk_bf16_f32(lo, hi);   // v_cvt_pk_bf16_f32 (RNE)
  union { decltype(r) v; uint32_t u; } c; c.v = r; return c.u;
#else
  union { float f; uint32_t i; } a, b; a.f = lo; b.f = hi;
  uint32_t ua = a.i + 0x7FFFu + ((a.i >> 16) & 1u);
  uint32_t ub = b.i + 0x7FFFu + ((b.i >> 16) & 1u);
  return (ua >> 16) | (ub & 0xFFFF0000u);
#endif
}

// ---- preprocess: exact LDS image per (layer,node): Wt[j][k] bf16, stride LDP;
// row k==KSRC carries the bias (augmented-K); everything else 0.
__global__ __launch_bounds__(256) void prep_weights(
    const float* __restrict__ W_in, const float* __restrict__ b_in,
    const float* __restrict__ W_hid, const float* __restrict__ b_hid,
    ushort* __restrict__ wt)
{
  __shared__ float ldsw[kH][kH + 1];
  __shared__ float ldsb[kH];
  const int tid   = threadIdx.x;
  const int node  = blockIdx.x & (kN - 1);
  const int layer = blockIdx.x >> 7;               // 0..3
  const int ksrc  = (layer == 0) ? kE : kH;
  const float* src;
  const float* bsrc;
  if (layer == 0) { src = W_in + (size_t)node * kE * kH; bsrc = b_in + (size_t)node * kH; }
  else {
    int l = layer - 1;
    src  = W_hid + (size_t)(l * kN + node) * kH * kH;
    bsrc = b_hid + (size_t)(l * kN + node) * kH;
  }
  for (int idx = tid; idx < ksrc * kH; idx += 256)
    ldsw[idx / kH][idx % kH] = src[idx];
  if (tid < kH) ldsb[tid] = bsrc[tid];
  __syncthreads();
  ushort* dst = wt + (size_t)blockIdx.x * TILE_ELEMS;
  for (int idx = tid; idx < TILE_ELEMS; idx += 256) {
    int j = idx / LDP, k = idx % LDP;
    float v = 0.f;
    if (j < kH) {
      if (k < ksrc)       v = ldsw[k][j];
      else if (k == ksrc) v = ldsb[j];
    }
    dst[idx] = f2bf(v);
  }
}

// wout image per node: [0..89]=W_out, [90]=b_out, rest 0.
__global__ __launch_bounds__(256) void prep_wout(
    const float* __restrict__ W_out, const float* __restrict__ b_out,
    ushort* __restrict__ wo)
{
  int idx = blockIdx.x * 256 + threadIdx.x;
  int node = idx / KP, j = idx % KP;
  float v = 0.f;
  if (j < kH)       v = W_out[node * kH + j];
  else if (j == kH) v = b_out[node];
  wo[idx] = f2bf(v);
}

// 128 threads = 2 waves. Wave w owns batch cols w*64..w*64+63 (4 n-tiles of 16),
// all 96 j_out (6 m-tiles). A=weights, B=activations:
//   D col=lane&15 -> batch, row=quad*4+r -> j_out (4 consecutive => b64 writes).
__global__ __launch_bounds__(128) void dnpu_kernel(
    const float* __restrict__ x, const float* __restrict__ controls,
    const ushort* __restrict__ wt, const ushort* __restrict__ wo,
    float* __restrict__ out)
{
  __shared__ __align__(16) ushort hbuf[BT][LDP];  // activations [batch][k] bf16
  __shared__ __align__(16) ushort wbuf[KP][LDP];  // Wt[j_out][k_in] bf16
  __shared__ __align__(16) ushort wobuf[KP];

  const int tid   = threadIdx.x;
  const int node  = (int)(blockIdx.x >> 7);        // resident blocks share few nodes
  const int m0    = (int)(blockIdx.x & 127) * BT;
  const int wave  = tid >> 6;
  const int lane  = tid & 63;
  const int quad  = lane >> 4;
  const int l16   = lane & 15;
  const int nbase = wave * 64;

  auto stage_w = [&](int lyr) {
    const bf16x8* src = (const bf16x8*)(wt + (size_t)(lyr * kN + node) * TILE_ELEMS);
    bf16x8* dst = (bf16x8*)&wbuf[0][0];
#pragma unroll
    for (int it = 0; it < 10; ++it) {
      int c = tid + it * 128;
      if (c < TILE_CHUNKS) dst[c] = src[c];
    }
  };

  // ---- stage input: row tid = [x0,x1,x2,c0,c1,c2,c3,1.0, 0 x24] ----
  {
    const float* xr = x + (size_t)(m0 + tid) * (kN * kI) + node * kI;
    float c0 = controls[node * kC + 0], c1 = controls[node * kC + 1];
    float c2 = controls[node * kC + 2], c3 = controls[node * kC + 3];
    uint4 v;
    v.x = pack_bf16(xr[0], xr[1]);
    v.y = pack_bf16(xr[2], c0);
    v.z = pack_bf16(c1, c2);
    v.w = pack_bf16(c3, 1.0f);
    *(uint4*)&hbuf[tid][0]  = v;
    uint4 z = {0, 0, 0, 0};
    *(uint4*)&hbuf[tid][8]  = z;
    *(uint4*)&hbuf[tid][16] = z;
    *(uint4*)&hbuf[tid][24] = z;
  }
  stage_w(0);
  if (tid < KP / 8) ((bf16x8*)wobuf)[tid] = ((const bf16x8*)(wo + node * KP))[tid];
  __syncthreads();

  f32x4 acc[6][4];   // [m-tile(j_out)][n-tile(batch)] = 96 VGPRs
  auto zero_acc = [&]() {
#pragma unroll
    for (int mt = 0; mt < 6; ++mt)
#pragma unroll
      for (int nt = 0; nt < 4; ++nt)
        acc[mt][nt] = (f32x4){0.f, 0.f, 0.f, 0.f};
  };

  // A[m=l16][k=quad*8+j] <- wbuf[j_out][k]; B[k=quad*8+j][n=l16] <- hbuf[batch][k]
  auto run_gemm = [&](int ksteps) {
    for (int ks = 0; ks < ksteps; ++ks) {
      const int koff = ks * 32 + quad * 8;
      bf16x8 bfr[4];
#pragma unroll
      for (int nt = 0; nt < 4; ++nt)
        bfr[nt] = *(const bf16x8*)&hbuf[nbase + nt * 16 + l16][koff];
#pragma unroll
      for (int mt = 0; mt < 6; ++mt) {
        bf16x8 afr = *(const bf16x8*)&wbuf[mt * 16 + l16][koff];
#pragma unroll
        for (int nt = 0; nt < 4; ++nt)
          acc[mt][nt] = __builtin_amdgcn_mfma_f32_16x16x32_bf16(afr, bfr[nt], acc[mt][nt], 0, 0, 0);
      }
    }
  };

  // relu(acc) -> hbuf[batch][j_out], 4 consecutive j_out per lane => b64 write.
  // j_out==90 (mt=5,quad=2,r=2) := 1.0 (bias row for the next layer's augmented K).
  auto write_h = [&]() {
#pragma unroll
    for (int mt = 0; mt < 6; ++mt)
#pragma unroll
      for (int nt = 0; nt < 4; ++nt) {
        float v0 = fmaxf(acc[mt][nt][0], 0.f);
        float v1 = fmaxf(acc[mt][nt][1], 0.f);
        float v2 = fmaxf(acc[mt][nt][2], 0.f);
        float v3 = fmaxf(acc[mt][nt][3], 0.f);
        if (mt == 5 && quad == 2) v2 = 1.0f;     // j_out = 90
        uint2 p;
        p.x = pack_bf16(v0, v1);
        p.y = pack_bf16(v2, v3);
        *(uint2*)&hbuf[nbase + nt * 16 + l16][mt * 16 + quad * 4] = p;
      }
  };

  zero_acc();
  run_gemm(1);   // input layer, K=32

  for (int l = 0; l < kL; ++l) {
    __syncthreads();          // both waves done reading wbuf
    write_h();                // own batch rows only (no cross-wave hazard)
    stage_w(l + 1);
    zero_acc();
    __syncthreads();
    run_gemm(3);              // K=96 (k=90 carries bias, 91..95 zero)
  }

  __syncthreads();
  write_h();                  // h3 -> hbuf (col 90 = 1.0 pairs with wobuf[90]=b_out)
  __syncthreads();

  // out[b][node] = h3 . wout  — rotated chunk order breaks the 8-way row-stride conflict
  {
    float sum = 0.f;
#pragma unroll
    for (int cc = 0; cc < 12; ++cc) {
      int c = ((cc + tid) % 12) * 8;
      bf16x8 hv = *(const bf16x8*)&hbuf[tid][c];
      bf16x8 wv = *(const bf16x8*)&wobuf[c];
#pragma unroll
      for (int j = 0; j < 8; ++j)
        sum += bf2f((ushort)hv[j]) * bf2f((ushort)wv[j]);
    }
    out[(size_t)(m0 + tid) * kN + node] = sum;
  }
}

extern "C" void kernel_launch(void* const* d_in, const int* in_sizes, int n_in,
                              void* d_out, int out_size, void* d_ws, size_t ws_size,
                              hipStream_t stream) {
  const float* x        = (const float*)d_in[0];
  const float* controls = (const float*)d_in[1];
  const float* W_in     = (const float*)d_in[2];
  const float* b_in     = (const float*)d_in[3];
  const float* W_hid    = (const float*)d_in[4];
  const float* b_hid    = (const float*)d_in[5];
  const float* W_out    = (const float*)d_in[6];
  const float* b_out    = (const float*)d_in[7];
  float* out = (float*)d_out;

  ushort* wtw = (ushort*)d_ws;
  ushort* wo  = (ushort*)((char*)d_ws + WOUT_OFF);

  hipLaunchKernelGGL(prep_weights, dim3(4 * kN), dim3(256), 0, stream,
                     W_in, b_in, W_hid, b_hid, wtw);
  hipLaunchKernelGGL(prep_wout, dim3(kN * KP / 256), dim3(256), 0, stream,
                     W_out, b_out, wo);

  dim3 grid((kB / BT) * kN);   // bid = node*128 + m_tile
  hipLaunchKernelGGL(dnpu_kernel, grid, dim3(128), 0, stream,
                     x, controls, wtw, wo, out);
}

// Round 6
// 252.247 us; speedup vs baseline: 3.9490x; 1.5539x over previous
//
#include <hip/hip_runtime.h>
#include <stdint.h>

namespace {
constexpr int kB  = 16384;  // batch
constexpr int kN  = 128;    // nodes
constexpr int kI  = 3;      // data electrodes
constexpr int kC  = 4;      // control electrodes
constexpr int kH  = 90;     // hidden width
constexpr int kL  = 3;      // hidden layers
constexpr int BT  = 64;     // batch rows per block (1 wave)
constexpr int KP  = 96;     // padded H
constexpr int LDP = 104;    // hbuf row stride (208 B, 16B-aligned, 2-way-bank-free)
// A-fragment-contiguous weight tile: 18 frag-blocks (fb=ks*6+mt) x 1024 B.
// Frag fb, lane l (quad=l>>4,l16=l&15): 8 bf16 = Wt[mt*16+l16][ks*32+quad*8 .. +7]
// where Wt[j][k] = W_src[k][j], row k==ksrc = bias (augmented-K), else 0.
constexpr int TILE_USH = 18 * 512;                 // 9216 ushorts = 18432 B
constexpr size_t WT_BYTES = (size_t)4 * kN * TILE_USH * 2;   // 9,437,184
constexpr size_t WOUT_OFF = WT_BYTES;              // float wo[128][96]
}

typedef __attribute__((ext_vector_type(8))) short bf16x8;
typedef __attribute__((ext_vector_type(4))) float f32x4;

__device__ __forceinline__ uint32_t pack_bf16(float lo, float hi) {
#if __has_builtin(__builtin_amdgcn_cvt_pk_bf16_f32)
  auto r = __builtin_amdgcn_cvt_pk_bf16_f32(lo, hi);
  union { decltype(r) v; uint32_t u; } c; c.v = r; return c.u;
#else
  union { float f; uint32_t i; } a, b; a.f = lo; b.f = hi;
  uint32_t ua = a.i + 0x7FFFu + ((a.i >> 16) & 1u);
  uint32_t ub = b.i + 0x7FFFu + ((b.i >> 16) & 1u);
  return (ua >> 16) | (ub & 0xFFFF0000u);
#endif
}
__device__ __forceinline__ ushort f2bf(float f) {
  union { float f; uint32_t i; } v; v.f = f;
  uint32_t u = v.i + 0x7FFFu + ((v.i >> 16) & 1u);
  return (ushort)(u >> 16);
}

// ---- preprocess: A-frag-contiguous bf16 tiles + float wout image ----
__global__ __launch_bounds__(256) void prep_weights(
    const float* __restrict__ W_in, const float* __restrict__ b_in,
    const float* __restrict__ W_hid, const float* __restrict__ b_hid,
    const float* __restrict__ W_out, const float* __restrict__ b_out,
    ushort* __restrict__ wt, float* __restrict__ wo)
{
  const int tid = threadIdx.x;
  if (blockIdx.x >= 4 * kN) {   // wout image: [0..89]=W_out, [90]=b_out, 91..95=0
    int base = (int)(blockIdx.x - 4 * kN) * 3072;
    for (int t = 0; t < 12; ++t) {
      int idx = base + t * 256 + tid;          // 0..12287
      int node = idx / KP, j = idx % KP;
      float v = 0.f;
      if (j < kH)       v = W_out[node * kH + j];
      else if (j == kH) v = b_out[node];
      wo[idx] = v;
    }
    return;
  }
  __shared__ float ldsw[kH][kH + 1];
  __shared__ float ldsb[kH];
  const int node  = blockIdx.x & (kN - 1);
  const int layer = blockIdx.x >> 7;               // 0..3
  const int ksrc  = (layer == 0) ? (kI + kC) : kH; // 7 or 90
  const float* src;
  const float* bsrc;
  if (layer == 0) { src = W_in + (size_t)node * (kI + kC) * kH; bsrc = b_in + (size_t)node * kH; }
  else {
    int l = layer - 1;
    src  = W_hid + (size_t)(l * kN + node) * kH * kH;
    bsrc = b_hid + (size_t)(l * kN + node) * kH;
  }
  for (int idx = tid; idx < ksrc * kH; idx += 256)   // coalesced; LDS as [k][j]
    ldsw[idx / kH][idx % kH] = src[idx];
  if (tid < kH) ldsb[tid] = bsrc[tid];
  __syncthreads();
  ushort* dst = wt + (size_t)blockIdx.x * TILE_USH;  // blockIdx = layer*128+node
  const int nush = (layer == 0) ? 6 * 512 : TILE_USH; // layer0: only fb 0..5 used
  for (int idx = tid; idx < nush; idx += 256) {
    int fb = idx >> 9, lane = (idx >> 3) & 63, i = idx & 7;
    int mt = fb % 6, ks = fb / 6;
    int j = mt * 16 + (lane & 15);
    int k = ks * 32 + (lane >> 4) * 8 + i;
    float v = 0.f;
    if (j < kH) {
      if (k < ksrc)       v = ldsw[k][j];
      else if (k == ksrc) v = ldsb[j];
    }
    dst[idx] = f2bf(v);
  }
}

// ---- main: 1 wave per block, 64 batch rows, weights direct from global.
// A=weights, B=activations: D col=l16 -> batch, row=quad*4+r -> j_out.
// hbuf is wave-private => NO barriers anywhere.
__global__ __launch_bounds__(64, 3) void dnpu_kernel(
    const float* __restrict__ x, const float* __restrict__ controls,
    const ushort* __restrict__ wt, const float* __restrict__ wo,
    float* __restrict__ out)
{
  __shared__ __align__(16) ushort hbuf[BT][LDP];   // activations [batch][k] bf16

  const int lane = threadIdx.x;                    // 0..63
  const int node = (int)(blockIdx.x & 127);        // CU-resident blocks share a node
  const int m0   = (int)(blockIdx.x >> 7) * BT;
  const int quad = lane >> 4;
  const int l16  = lane & 15;

  // ---- stage input: row lane = [x0,x1,x2,c0..c3,1.0, 0 x24] ----
  {
    const float* xr = x + (size_t)(m0 + lane) * (kN * kI) + node * kI;
    float x0 = xr[0], x1 = xr[1], x2 = xr[2];
    float c0 = controls[node * kC + 0], c1 = controls[node * kC + 1];
    float c2 = controls[node * kC + 2], c3 = controls[node * kC + 3];
    uint4 v;
    v.x = pack_bf16(x0, x1);
    v.y = pack_bf16(x2, c0);
    v.z = pack_bf16(c1, c2);
    v.w = pack_bf16(c3, 1.0f);
    *(uint4*)&hbuf[lane][0]  = v;
    uint4 z = {0, 0, 0, 0};
    *(uint4*)&hbuf[lane][8]  = z;
    *(uint4*)&hbuf[lane][16] = z;
    *(uint4*)&hbuf[lane][24] = z;
  }

  f32x4 acc[6][4];   // [m-tile(j_out)][n-tile(batch)]
  auto zero_acc = [&]() {
#pragma unroll
    for (int mt = 0; mt < 6; ++mt)
#pragma unroll
      for (int nt = 0; nt < 4; ++nt)
        acc[mt][nt] = (f32x4){0.f, 0.f, 0.f, 0.f};
  };

  // A-frags streamed straight from global (L1-hot, 1 KB contiguous per frag)
  auto run_gemm = [&](const ushort* tl, int ksteps) {
    for (int ks = 0; ks < ksteps; ++ks) {
      bf16x8 bfr[4];
#pragma unroll
      for (int nt = 0; nt < 4; ++nt)
        bfr[nt] = *(const bf16x8*)&hbuf[nt * 16 + l16][ks * 32 + quad * 8];
      bf16x8 afr[6];
#pragma unroll
      for (int mt = 0; mt < 6; ++mt)
        afr[mt] = *(const bf16x8*)&tl[(size_t)(ks * 6 + mt) * 512 + lane * 8];
#pragma unroll
      for (int mt = 0; mt < 6; ++mt)
#pragma unroll
        for (int nt = 0; nt < 4; ++nt)
          acc[mt][nt] = __builtin_amdgcn_mfma_f32_16x16x32_bf16(afr[mt], bfr[nt], acc[mt][nt], 0, 0, 0);
    }
  };

  // relu(acc) -> hbuf[batch][j_out]; j_out==90 := 1.0 (bias row for next K)
  auto write_h = [&]() {
#pragma unroll
    for (int mt = 0; mt < 6; ++mt)
#pragma unroll
      for (int nt = 0; nt < 4; ++nt) {
        float v0 = fmaxf(acc[mt][nt][0], 0.f);
        float v1 = fmaxf(acc[mt][nt][1], 0.f);
        float v2 = fmaxf(acc[mt][nt][2], 0.f);
        float v3 = fmaxf(acc[mt][nt][3], 0.f);
        if (mt == 5 && quad == 2) v2 = 1.0f;       // j_out = 90
        uint2 p;
        p.x = pack_bf16(v0, v1);
        p.y = pack_bf16(v2, v3);
        *(uint2*)&hbuf[nt * 16 + l16][mt * 16 + quad * 4] = p;
      }
  };

  const ushort* t0 = wt + (size_t)(0 * kN + node) * TILE_USH;
  zero_acc();
  run_gemm(t0, 1);                                 // input layer, K=32

#pragma unroll
  for (int l = 0; l < kL; ++l) {
    write_h();
    zero_acc();
    run_gemm(wt + (size_t)((l + 1) * kN + node) * TILE_USH, 3);  // K=96
  }

  // ---- final dot in registers: out = relu(h3) . wout (+ b_out via j=90) ----
  {
    float4 wof[6];
#pragma unroll
    for (int mt = 0; mt < 6; ++mt)
      wof[mt] = *(const float4*)&wo[node * KP + mt * 16 + quad * 4];
    float s0 = 0.f, s1 = 0.f, s2 = 0.f, s3 = 0.f;
#pragma unroll
    for (int mt = 0; mt < 6; ++mt) {
      float w0 = wof[mt].x, w1 = wof[mt].y, w2 = wof[mt].z, w3 = wof[mt].w;
#pragma unroll
      for (int nt = 0; nt < 4; ++nt) {
        float h0 = fmaxf(acc[mt][nt][0], 0.f);
        float h1 = fmaxf(acc[mt][nt][1], 0.f);
        float h2 = fmaxf(acc[mt][nt][2], 0.f);
        float h3 = fmaxf(acc[mt][nt][3], 0.f);
        if (mt == 5 && quad == 2) h2 = 1.0f;       // j=90 pairs with wout[90]=b_out
        float p = h0 * w0 + h1 * w1 + h2 * w2 + h3 * w3;
        if (nt == 0) s0 += p; else if (nt == 1) s1 += p;
        else if (nt == 2) s2 += p; else s3 += p;
      }
    }
    s0 += __shfl_xor(s0, 16); s0 += __shfl_xor(s0, 32);
    s1 += __shfl_xor(s1, 16); s1 += __shfl_xor(s1, 32);
    s2 += __shfl_xor(s2, 16); s2 += __shfl_xor(s2, 32);
    s3 += __shfl_xor(s3, 16); s3 += __shfl_xor(s3, 32);
    float r = (quad == 0) ? s0 : (quad == 1) ? s1 : (quad == 2) ? s2 : s3;
    int col = quad * 16 + l16;                     // nt == quad
    out[(size_t)(m0 + col) * kN + node] = r;
  }
}

extern "C" void kernel_launch(void* const* d_in, const int* in_sizes, int n_in,
                              void* d_out, int out_size, void* d_ws, size_t ws_size,
                              hipStream_t stream) {
  const float* x        = (const float*)d_in[0];
  const float* controls = (const float*)d_in[1];
  const float* W_in     = (const float*)d_in[2];
  const float* b_in     = (const float*)d_in[3];
  const float* W_hid    = (const float*)d_in[4];
  const float* b_hid    = (const float*)d_in[5];
  const float* W_out    = (const float*)d_in[6];
  const float* b_out    = (const float*)d_in[7];
  float* out = (float*)d_out;

  ushort* wt = (ushort*)d_ws;
  float*  wo = (float*)((char*)d_ws + WOUT_OFF);

  hipLaunchKernelGGL(prep_weights, dim3(4 * kN + 4), dim3(256), 0, stream,
                     W_in, b_in, W_hid, b_hid, W_out, b_out, wt, wo);

  dim3 grid((kB / BT) * kN);   // bid = tile*128 + node -> 32768 one-wave blocks
  hipLaunchKernelGGL(dnpu_kernel, grid, dim3(BT), 0, stream,
                     x, controls, wt, wo, out);
}